// Round 11
// baseline (74.005 us; speedup 1.0000x reference)
//
#include <hip/hip_runtime.h>

// CRF-RNN collapsed: out[t,i] = sum_j M[i,j] * orig[t,j],
//   orig[t,j] = sum_m inputs[t,j,m]*W_feat[m]
//   M = (I + B + B^2 + B^3) * diag(1/denom) + B^4
// 4 dispatches:
//   k_prep    -> B (fp32), Einv
//   k_mm      -> C = B^2
//   k_mm2comb -> G1,G2 rows in-register -> Mh/Ml (split bf16)
//   k_fused   -> stream input (VGPR loads, full MLP) -> split-bf16 A in LDS
//                -> 8x 32-j M-panels via global_load_lds -> MFMA -> out

#define NREG 256   // N
#define KG   16    // gaussian kernels
#define MF   8     // features

typedef unsigned short u16;
typedef __attribute__((ext_vector_type(8))) short short8;   // 8 bf16 = 4 VGPR
typedef __attribute__((ext_vector_type(4))) float f32x4;

__device__ __forceinline__ void async_copy16(const void* g, void* l) {
    __builtin_amdgcn_global_load_lds(
        (const __attribute__((address_space(1))) void*)g,
        (__attribute__((address_space(3))) void*)l,
        16, 0, 0);
}

__device__ __forceinline__ u16 bf16_rne(float x) {
    unsigned u = __float_as_uint(x);
    return (u16)((u + 0x7FFFu + ((u >> 16) & 1u)) >> 16);
}
__device__ __forceinline__ float bf16_to_f(u16 h) {
    return __uint_as_float(((unsigned)h) << 16);
}

// ---------------- K1: Kmat row, denom, B, Einv ----------------
__global__ __launch_bounds__(256) void k_prep(const float* __restrict__ kern,
                                              const float* __restrict__ Wlin,
                                              const float* __restrict__ Wfeat,
                                              float* __restrict__ B,
                                              float* __restrict__ Einv) {
    const int i = blockIdx.x, j = threadIdx.x;
    const float* kp = kern + ((size_t)i * NREG + j) * KG;
    float4 w0 = *(const float4*)(Wlin + 0);
    float4 w1 = *(const float4*)(Wlin + 4);
    float4 w2 = *(const float4*)(Wlin + 8);
    float4 w3 = *(const float4*)(Wlin + 12);
    float4 v0 = *(const float4*)(kp + 0);
    float4 v1 = *(const float4*)(kp + 4);
    float4 v2 = *(const float4*)(kp + 8);
    float4 v3 = *(const float4*)(kp + 12);
    float km = v0.x*w0.x + v0.y*w0.y + v0.z*w0.z + v0.w*w0.w
             + v1.x*w1.x + v1.y*w1.y + v1.z*w1.z + v1.w*w1.w
             + v2.x*w2.x + v2.y*w2.y + v2.z*w2.z + v2.w*w2.w
             + v3.x*w3.x + v3.y*w3.y + v3.z*w3.z + v3.w*w3.w;

    __shared__ float red[256];
    red[j] = km;
    __syncthreads();
    for (int s = 128; s > 0; s >>= 1) {
        if (j < s) red[j] += red[j + s];
        __syncthreads();
    }
    __shared__ float sden;
    if (j == 0) {
        float fw = 0.f;
#pragma unroll
        for (int m = 0; m < MF; ++m) fw += Wfeat[m];
        float den = fw + 2.f * red[0];
        sden = den;
        Einv[i] = 1.f / den;
    }
    __syncthreads();
    B[(size_t)i * NREG + j] = 2.f * km / sden;
}

// ---------------- 2-row matmul helper: acc pair = A-rows(i0,i0+1) * Bm -----
#define MM2_BODY(Ar, Bm, acc0, acc1)                                          \
    _Pragma("unroll 2")                                                       \
    for (int l = 0; l < NREG; l += 8) {                                       \
        float b0 = Bm[(size_t)(l + 0) * NREG + tid];                          \
        float b1 = Bm[(size_t)(l + 1) * NREG + tid];                          \
        float b2 = Bm[(size_t)(l + 2) * NREG + tid];                          \
        float b3 = Bm[(size_t)(l + 3) * NREG + tid];                          \
        float b4 = Bm[(size_t)(l + 4) * NREG + tid];                          \
        float b5 = Bm[(size_t)(l + 5) * NREG + tid];                          \
        float b6 = Bm[(size_t)(l + 6) * NREG + tid];                          \
        float b7 = Bm[(size_t)(l + 7) * NREG + tid];                          \
        acc0 += Ar[0][l+0]*b0 + Ar[0][l+1]*b1 + Ar[0][l+2]*b2 + Ar[0][l+3]*b3 \
              + Ar[0][l+4]*b4 + Ar[0][l+5]*b5 + Ar[0][l+6]*b6 + Ar[0][l+7]*b7;\
        acc1 += Ar[1][l+0]*b0 + Ar[1][l+1]*b1 + Ar[1][l+2]*b2 + Ar[1][l+3]*b3 \
              + Ar[1][l+4]*b4 + Ar[1][l+5]*b5 + Ar[1][l+6]*b6 + Ar[1][l+7]*b7;\
    }

// K2: C = B*B   (grid 128, 2 rows/block)
__global__ __launch_bounds__(256) void k_mm(const float* __restrict__ A,
                                            const float* __restrict__ Bm,
                                            float* __restrict__ Out) {
    const int tid = threadIdx.x;
    const int i0 = blockIdx.x * 2;
    __shared__ float Ar[2][NREG];
    Ar[0][tid] = A[(size_t)i0 * NREG + tid];
    Ar[1][tid] = A[(size_t)(i0 + 1) * NREG + tid];
    __syncthreads();
    float acc0 = 0.f, acc1 = 0.f;
    MM2_BODY(Ar, Bm, acc0, acc1)
    Out[(size_t)i0 * NREG + tid] = acc0;
    Out[(size_t)(i0 + 1) * NREG + tid] = acc1;
}

// K3: G1 = B*C, G2 = C*C (rows i0,i0+1, in-register) -> Mh/Ml rows
__global__ __launch_bounds__(256) void k_mm2comb(const float* __restrict__ B,
                                                 const float* __restrict__ C,
                                                 const float* __restrict__ Einv,
                                                 u16* __restrict__ Mh,
                                                 u16* __restrict__ Ml) {
    const int tid = threadIdx.x;
    const int i0 = blockIdx.x * 2;
    __shared__ float Ar[2][NREG];

    Ar[0][tid] = B[(size_t)i0 * NREG + tid];
    Ar[1][tid] = B[(size_t)(i0 + 1) * NREG + tid];
    __syncthreads();
    float g1_0 = 0.f, g1_1 = 0.f;
    MM2_BODY(Ar, C, g1_0, g1_1)
    __syncthreads();                      // before overwriting Ar
    Ar[0][tid] = C[(size_t)i0 * NREG + tid];
    Ar[1][tid] = C[(size_t)(i0 + 1) * NREG + tid];
    __syncthreads();
    float g2_0 = 0.f, g2_1 = 0.f;
    MM2_BODY(Ar, C, g2_0, g2_1)

    const float einv = Einv[tid];
#pragma unroll
    for (int rr = 0; rr < 2; ++rr) {
        const int i = i0 + rr;
        const size_t idx = (size_t)i * NREG + tid;
        float g1 = rr ? g1_1 : g1_0;
        float g2 = rr ? g2_1 : g2_0;
        float v = ((i == tid) ? 1.f : 0.f) + B[idx] + C[idx] + g1;
        v = v * einv + g2;
        u16 h = bf16_rne(v);
        Mh[idx] = h;
        Ml[idx] = bf16_rne(v - bf16_to_f(h));
    }
}

// ---------------- K4: fused stream + MFMA GEMM -----------------------------
// 512 blocks x 256 thr (4 waves), 32 t-rows/block, 2 blocks/CU (64 KB LDS).
// Stage 1: plain VGPR loads (4 batches of 16 independent float4/thread ->
//          full memory-level parallelism, compiler-managed waitcnt),
//          feature-reduce, split-bf16, swizzled ds_write into Ah/Al.
// Stage 2: 8 panels of 32 j; Bh/Bl [256 i][4 chunks][8] staged via
//          global_load_lds with pre-swizzled source (chunk ^= (irow>>1)&3,
//          2-way bank alias = free); 3-product split-bf16 MFMA.
__global__ __launch_bounds__(256, 2) void k_fused(const float* __restrict__ in,
                                                  const float* __restrict__ Wfeat,
                                                  const u16* __restrict__ Mh,
                                                  const u16* __restrict__ Ml,
                                                  float* __restrict__ out) {
    __shared__ __align__(16) u16 Ah[32 * 256];   // 16 KB
    __shared__ __align__(16) u16 Al[32 * 256];   // 16 KB
    __shared__ __align__(16) u16 Bh[256 * 32];   // 16 KB (one 32-j panel)
    __shared__ __align__(16) u16 Bl[256 * 32];   // 16 KB
    const int tid = threadIdx.x, lane = tid & 63, wid = tid >> 6;  // wid 0..3
    const size_t t0 = (size_t)blockIdx.x * 32;

    float4 wa = *(const float4*)(Wfeat);
    float4 wb = *(const float4*)(Wfeat + 4);

    // ---- stage 1: thread (r = tid>>3, s = tid&7) covers row r, cell-pairs
    // j0 = q*16 + 2s (q = 0..15); 64 B contiguous per (thread,q).
    {
        const int r = tid >> 3, s = tid & 7;
        const float* rowp = in + (t0 + r) * (NREG * MF);
#pragma unroll
        for (int b = 0; b < 4; ++b) {
            float4 v[4][4];
#pragma unroll
            for (int qq = 0; qq < 4; ++qq) {
                const float* p = rowp + (b * 4 + qq) * 128 + s * 16;
#pragma unroll
                for (int k = 0; k < 4; ++k) v[qq][k] = *(const float4*)(p + k * 4);
            }
#pragma unroll
            for (int qq = 0; qq < 4; ++qq) {
                const int q = b * 4 + qq;
                float o0 = v[qq][0].x*wa.x + v[qq][0].y*wa.y + v[qq][0].z*wa.z + v[qq][0].w*wa.w
                         + v[qq][1].x*wb.x + v[qq][1].y*wb.y + v[qq][1].z*wb.z + v[qq][1].w*wb.w;
                float o1 = v[qq][2].x*wa.x + v[qq][2].y*wa.y + v[qq][2].z*wa.z + v[qq][2].w*wa.w
                         + v[qq][3].x*wb.x + v[qq][3].y*wb.y + v[qq][3].z*wb.z + v[qq][3].w*wb.w;
                u16 h0 = bf16_rne(o0), l0 = bf16_rne(o0 - bf16_to_f(h0));
                u16 h1 = bf16_rne(o1), l1 = bf16_rne(o1 - bf16_to_f(h1));
                const int j0 = q * 16 + 2 * s;
                const int cs = (j0 >> 3) ^ (r & 7);       // chunk swizzle
                const int idx = r * 256 + cs * 8 + (j0 & 7);   // even -> 4B ok
                *(unsigned*)&Ah[idx] = (unsigned)h0 | ((unsigned)h1 << 16);
                *(unsigned*)&Al[idx] = (unsigned)l0 | ((unsigned)l1 << 16);
            }
        }
    }

    // ---- stage 2: 8 panels of 32 j, single-buffered, barrier-bounded async
    const int m = wid >> 1, nh = (wid & 1) * 8;
    const int mrow = m * 16 + (lane & 15);
    const int bcs = (lane >> 4) ^ (((lane & 15) >> 1) & 3);  // B read chunk (lane-only)
    f32x4 acc[8];
#pragma unroll
    for (int n = 0; n < 8; ++n) acc[n] = (f32x4){0.f, 0.f, 0.f, 0.f};

    // stage panel p: per wave 8 gll (4 per split); instr g covers 16 i-rows.
    // lane l -> dest row i0r+(l>>2), slot l&3; source chunk = (l&3)^((l>>3)&3)
    auto stageB = [&](int p) {
#pragma unroll
        for (int s2 = 0; s2 < 4; ++s2) {
            const int i0r = (s2 * 4 + wid) * 16;
            const int irow = i0r + (lane >> 2);
            const int sc = (lane & 3) ^ ((lane >> 3) & 3);
            async_copy16(Mh + (size_t)irow * NREG + p * 32 + sc * 8,
                         Bh + i0r * 32);
            async_copy16(Ml + (size_t)irow * NREG + p * 32 + sc * 8,
                         Bl + i0r * 32);
        }
    };

    stageB(0);
    __syncthreads();     // drains vmcnt (panel 0) + lgkm (A writes)

    for (int p = 0; p < 8; ++p) {
        const int achunk = (p * 4 + (lane >> 4)) ^ (lane & 7);
        short8 a_h = *(const short8*)&Ah[mrow * 256 + achunk * 8];
        short8 a_l = *(const short8*)&Al[mrow * 256 + achunk * 8];
#pragma unroll
        for (int n = 0; n < 8; ++n) {
            const int irow = (nh + n) * 16 + (lane & 15);
            short8 b_h = *(const short8*)&Bh[irow * 32 + bcs * 8];
            short8 b_l = *(const short8*)&Bl[irow * 32 + bcs * 8];
            acc[n] = __builtin_amdgcn_mfma_f32_16x16x32_bf16(a_h, b_h, acc[n], 0, 0, 0);
            acc[n] = __builtin_amdgcn_mfma_f32_16x16x32_bf16(a_h, b_l, acc[n], 0, 0, 0);
            acc[n] = __builtin_amdgcn_mfma_f32_16x16x32_bf16(a_l, b_h, acc[n], 0, 0, 0);
        }
        if (p < 7) {
            __syncthreads();         // all waves done reading panel p
            stageB(p + 1);
            __syncthreads();         // panel p+1 resident
        }
    }

    // ---- epilogue: D col = lane&15 (i), row = (lane>>4)*4 + reg (t)
    const size_t tb = t0 + m * 16 + (lane >> 4) * 4;
#pragma unroll
    for (int n = 0; n < 8; ++n) {
#pragma unroll
        for (int r2 = 0; r2 < 4; ++r2) {
            out[(tb + r2) * NREG + (nh + n) * 16 + (lane & 15)] = acc[n][r2];
        }
    }
}

extern "C" void kernel_launch(void* const* d_in, const int* in_sizes, int n_in,
                              void* d_out, int out_size, void* d_ws, size_t ws_size,
                              hipStream_t stream) {
    const float* inputs  = (const float*)d_in[0];  // (16384, 256, 8)
    const float* kernels = (const float*)d_in[1];  // (256, 256, 16)
    const float* Wfeat   = (const float*)d_in[2];  // (1, 8)
    const float* Wlin    = (const float*)d_in[3];  // (1, 16)
    float* out = (float*)d_out;                    // (16384, 256)

    float* ws   = (float*)d_ws;                    // ~770 KB
    float* B    = ws;                              // 65536 f
    float* C    = B  + NREG * NREG;                // 65536 f (B^2)
    float* Einv = C  + NREG * NREG;                // 256 f
    u16*   Mh   = (u16*)(Einv + NREG);             // 65536 u16 (16B-aligned)
    u16*   Ml   = Mh + NREG * NREG;                // 65536 u16

    k_prep    <<<256, 256, 0, stream>>>(kernels, Wlin, Wfeat, B, Einv);
    k_mm      <<<128, 256, 0, stream>>>(B, B, C);
    k_mm2comb <<<128, 256, 0, stream>>>(B, C, Einv, Mh, Ml);
    k_fused   <<<512, 256, 0, stream>>>(inputs, Wfeat, Mh, Ml, out);
}